// Round 2
// baseline (147.293 us; speedup 1.0000x reference)
//
#include <hip/hip_runtime.h>
#include <math.h>

// Problem constants: B=8, C=64, H=W=64, O=128, K=3, N=9, stride=1, pad=1
// ws layout: rec (32768*9 uint4 = 4.5 MB) @ 0 ; Wt (9*64*128 f32 = 288 KB) @ 4718592
// total ws usage: 5,013,504 bytes  (round-1 failure was a ws overflow at 17.3 MB)

// ---------------------------------------------------------------------------
// Kernel T2: transpose conv_w (O,C,3,3) -> Wt (9, C, O)
// ---------------------------------------------------------------------------
__global__ __launch_bounds__(256) void k_transpose_w(const float* __restrict__ cw,
                                                     float* __restrict__ Wt) {
    int t = blockIdx.x * 256 + threadIdx.x;
    if (t >= 9 * 64 * 128) return;
    int o = t & 127;
    int c = (t >> 7) & 63;
    int n = t >> 13;
    Wt[t] = cw[(o * 64 + c) * 9 + n];
}

// ---------------------------------------------------------------------------
// Kernel S1: 27-channel 3x3 conv (pad 1) + gather-record precompute
//   grid 256 blocks x 256 threads; block = 128 pixels x 2 c-halves
//   record per (pix,n): uint4 { idx0|idx1<<12|gc0<<24|gc1<<28,
//                               idx2|idx3<<12|gc2<<24|gc3<<28,
//                               bitcast(mod), 0 }   with gc = (g+4)&15
// ---------------------------------------------------------------------------
__global__ __launch_bounds__(256) void k_stage1(
    const float* __restrict__ x, const float* __restrict__ shift_w,
    const float* __restrict__ shift_b, const float* __restrict__ mod_w,
    const float* __restrict__ mod_b, uint4* __restrict__ rec) {
    __shared__ float wl[576 * 28];   // [c*9+tap][ch(27, pad 28)] ; reused as cbuf later
    int t = threadIdx.x;

    // stage weights transposed into LDS (shift: ch 0..17, mod: ch 18..26)
    for (int l = t; l < 18 * 576; l += 256) {
        int ch = l / 576, r = l % 576;
        wl[r * 28 + ch] = shift_w[l];
    }
    for (int l = t; l < 9 * 576; l += 256) {
        int ch = l / 576, r = l % 576;
        wl[r * 28 + 18 + ch] = mod_w[l];
    }
    __syncthreads();

    int pixl = t & 127;
    int half = t >> 7;
    int pix = blockIdx.x * 128 + pixl;
    int b = pix >> 12;
    int ii = (pix >> 6) & 63;
    int jj = pix & 63;
    const float* xb = x + ((size_t)b << 18);

    float acc[27];
#pragma unroll
    for (int q = 0; q < 27; ++q) acc[q] = 0.f;

    int c0 = half * 32;
    for (int c = c0; c < c0 + 32; ++c) {
        const float* xc = xb + ((size_t)c << 12);
#pragma unroll
        for (int tap = 0; tap < 9; ++tap) {
            int yi = ii + tap / 3 - 1;
            int yj = jj + tap % 3 - 1;
            float xv = 0.f;
            if ((unsigned)yi < 64u && (unsigned)yj < 64u) xv = xc[yi * 64 + yj];
            float wv[28];
            const float4* wr4 = (const float4*)&wl[(c * 9 + tap) * 28];
#pragma unroll
            for (int q4 = 0; q4 < 7; ++q4) *(float4*)&wv[q4 * 4] = wr4[q4];
#pragma unroll
            for (int ch = 0; ch < 27; ++ch) acc[ch] = fmaf(wv[ch], xv, acc[ch]);
        }
    }

    __syncthreads();                 // wl reads done; safe to reuse as cbuf
    float* cbuf = wl;                // 128*27 floats
    if (half == 1) {
#pragma unroll
        for (int q = 0; q < 27; ++q) cbuf[pixl * 27 + q] = acc[q];
    }
    __syncthreads();
    if (half == 0) {
#pragma unroll
        for (int q = 0; q < 27; ++q) acc[q] += cbuf[pixl * 27 + q];

#pragma unroll
        for (int n = 0; n < 9; ++n) {
            // pos = (offset + pn) + p0, in exact reference order
            float px = ((acc[n] + shift_b[n]) + (float)(n / 3 - 1)) + (float)(ii + 1);
            float py = ((acc[9 + n] + shift_b[9 + n]) + (float)(n % 3 - 1)) + (float)(jj + 1);
            float mz = acc[18 + n] + mod_b[n];
            float mod = 1.f / (1.f + expf(-mz));

            float fx = floorf(px), fy = floorf(py);
            int ltx = (int)fminf(fmaxf(fx, 0.f), 63.f);
            int lty = (int)fminf(fmaxf(fy, 0.f), 63.f);
            int rbx = (int)fminf(fmaxf(fx + 1.f, 0.f), 63.f);
            int rby = (int)fminf(fmaxf(fy + 1.f, 0.f), 63.f);
            int pxi = (int)fminf(fmaxf(px, 0.f), 63.f);
            int pyi = (int)fminf(fmaxf(py, 0.f), 63.f);

            // reference's integer-valued weights (replicated exactly, quirks included)
            int g_lt = (1 + ltx - pxi) * (1 + lty - pyi);
            int g_rb = (1 - rbx + pxi) * (1 - rby + pyi);
            int g_lb = (1 + ltx - pxi) * (1 + rby - pyi);
            int g_rt = (1 - rbx + pxi) * (1 - lty + pyi);

            int qxa[4] = {ltx, rbx, ltx, rbx};
            int qya[4] = {lty, rby, rby, lty};
            int gga[4] = {g_lt, g_rb, g_lb, g_rt};
            unsigned uw[2] = {0u, 0u};
#pragma unroll
            for (int j = 0; j < 4; ++j) {
                // coords are into the padded plane; row/col 0 is the zero pad
                bool valid = (qxa[j] >= 1) && (qya[j] >= 1);
                unsigned idx = valid ? (unsigned)((qxa[j] - 1) * 64 + (qya[j] - 1)) : 0u;
                unsigned gc = (unsigned)(((valid ? gga[j] : 0) + 4) & 15);
                uw[j >> 1] |= (idx << ((j & 1) * 12)) | (gc << (24 + (j & 1) * 4));
            }
            rec[(size_t)pix * 9 + n] =
                make_uint4(uw[0], uw[1], __float_as_uint(mod), 0u);
        }
    }
}

// ---------------------------------------------------------------------------
// Kernel B: main GEMM.  out[pix][o] = sum_n sum_c A_n[pix][c] * W_n[c][o]
//   block: 128 pixels x 128 outputs, 256 threads, 8x8 register tile
//   A_n gathered directly from NCHW x (per-wave channel slab, lane = pixel pair)
//   A stored c-major in LDS with XOR granule swizzle -> conflict-free b128 reads
// ---------------------------------------------------------------------------
__global__ __launch_bounds__(256) void k_main(
    const float* __restrict__ x, const float* __restrict__ Wt,
    const uint4* __restrict__ rec, float* __restrict__ out) {
    __shared__ float Wl[64 * 128];   // [c][o]
    __shared__ float Al[64 * 128];   // [c][m] swizzled
    int t = threadIdx.x;
    int pix0 = blockIdx.x * 128;
    int b = pix0 >> 12;
    int pbase = pix0 & 4095;
    const float* xb = x + ((size_t)b << 18);

    float acc[8][8];
#pragma unroll
    for (int i = 0; i < 8; ++i)
#pragma unroll
        for (int j = 0; j < 8; ++j) acc[i][j] = 0.f;

    int tx = t & 15, ty = t >> 4;
    int m0 = tx * 8, o0 = ty * 8;
    int lane = t & 63, wave = t >> 6;
    int mA = lane * 2;               // this lane builds A rows for pixels mA, mA+1

    for (int n = 0; n < 9; ++n) {
        // stage W_n slab (64x128 f32 = 32 KB), linear, coalesced
        const float4* wsrc = (const float4*)(Wt + n * 8192);
#pragma unroll
        for (int r = 0; r < 8; ++r) ((float4*)Wl)[r * 256 + t] = wsrc[r * 256 + t];

        // fetch + decode the two gather records
        uint4 r0 = rec[(size_t)(pix0 + mA) * 9 + n];
        uint4 r1 = rec[(size_t)(pix0 + mA + 1) * 9 + n];
        int id0[4], id1[4];
        float w0[4], w1[4];
        float mf0 = __uint_as_float(r0.z);
        float mf1 = __uint_as_float(r1.z);
        {
            unsigned a0 = r0.x, b0 = r0.y, a1 = r1.x, b1 = r1.y;
            id0[0] = a0 & 0xFFF; id0[1] = (a0 >> 12) & 0xFFF;
            id0[2] = b0 & 0xFFF; id0[3] = (b0 >> 12) & 0xFFF;
            id1[0] = a1 & 0xFFF; id1[1] = (a1 >> 12) & 0xFFF;
            id1[2] = b1 & 0xFFF; id1[3] = (b1 >> 12) & 0xFFF;
            w0[0] = (float)((int)((a0 >> 24) & 15) - 4) * mf0;
            w0[1] = (float)((int)((a0 >> 28) & 15) - 4) * mf0;
            w0[2] = (float)((int)((b0 >> 24) & 15) - 4) * mf0;
            w0[3] = (float)((int)((b0 >> 28) & 15) - 4) * mf0;
            w1[0] = (float)((int)((a1 >> 24) & 15) - 4) * mf1;
            w1[1] = (float)((int)((a1 >> 28) & 15) - 4) * mf1;
            w1[2] = (float)((int)((b1 >> 24) & 15) - 4) * mf1;
            w1[3] = (float)((int)((b1 >> 28) & 15) - 4) * mf1;
        }

        // build A_n tile: each wave owns 16 channel planes, lane = 2 pixels
        int colb = (mA >> 2);        // granule of this lane's pixel pair
        int coff = (mA & 3);
#pragma unroll 4
        for (int cc = 0; cc < 16; ++cc) {
            int c = wave * 16 + cc;
            const float* xc = xb + ((size_t)c << 12);
            float a0 = w0[0] * xc[id0[0]];
            float a1 = w1[0] * xc[id1[0]];
            a0 = fmaf(w0[1], xc[id0[1]], a0);
            a1 = fmaf(w1[1], xc[id1[1]], a1);
            a0 = fmaf(w0[2], xc[id0[2]], a0);
            a1 = fmaf(w1[2], xc[id1[2]], a1);
            a0 = fmaf(w0[3], xc[id0[3]], a0);
            a1 = fmaf(w1[3], xc[id1[3]], a1);
            int col = ((colb ^ (c >> 3)) << 2) + coff;
            *(float2*)&Al[c * 128 + col] = make_float2(a0, a1);
        }
        __syncthreads();

        // inner GEMM over K=64
#pragma unroll 8
        for (int kk = 0; kk < 64; ++kk) {
            int sw = (kk >> 3) & 7;
            const float* arow = &Al[kk * 128];
            float4 av0 = *(const float4*)&arow[((tx * 2) ^ sw) << 2];
            float4 av1 = *(const float4*)&arow[((tx * 2 + 1) ^ sw) << 2];
            const float* wrow = &Wl[kk * 128 + o0];
            float4 wv0 = *(const float4*)wrow;
            float4 wv1 = *(const float4*)(wrow + 4);
            float am[8] = {av0.x, av0.y, av0.z, av0.w, av1.x, av1.y, av1.z, av1.w};
            float wo[8] = {wv0.x, wv0.y, wv0.z, wv0.w, wv1.x, wv1.y, wv1.z, wv1.w};
#pragma unroll
            for (int i = 0; i < 8; ++i)
#pragma unroll
                for (int j = 0; j < 8; ++j) acc[i][j] = fmaf(am[i], wo[j], acc[i][j]);
        }
        __syncthreads();
    }

    // epilogue: coalesced float4 stores along pixels
    float* ob = out + ((size_t)b << 19);
#pragma unroll
    for (int j = 0; j < 8; ++j) {
        int o = o0 + j;
        float4 lo = make_float4(acc[0][j], acc[1][j], acc[2][j], acc[3][j]);
        float4 hi = make_float4(acc[4][j], acc[5][j], acc[6][j], acc[7][j]);
        float* dst = ob + ((size_t)o << 12) + pbase + m0;
        *(float4*)dst = lo;
        *(float4*)(dst + 4) = hi;
    }
}

// ---------------------------------------------------------------------------
extern "C" void kernel_launch(void* const* d_in, const int* in_sizes, int n_in,
                              void* d_out, int out_size, void* d_ws, size_t ws_size,
                              hipStream_t stream) {
    const float* x = (const float*)d_in[0];
    const float* shift_w = (const float*)d_in[1];
    const float* shift_b = (const float*)d_in[2];
    const float* mod_w = (const float*)d_in[3];
    const float* mod_b = (const float*)d_in[4];
    const float* conv_w = (const float*)d_in[5];
    float* out = (float*)d_out;

    char* ws = (char*)d_ws;
    uint4* rec = (uint4*)ws;                       // 4.5 MB
    float* Wt = (float*)(ws + 4718592);            // 288 KB  (total 5.01 MB)

    k_transpose_w<<<dim3(288), dim3(256), 0, stream>>>(conv_w, Wt);
    k_stage1<<<dim3(256), dim3(256), 0, stream>>>(x, shift_w, shift_b, mod_w,
                                                  mod_b, rec);
    k_main<<<dim3(256), dim3(256), 0, stream>>>(x, Wt, rec, out);
}

// Round 3
// 93.018 us; speedup vs baseline: 1.5835x; 1.5835x over previous
//
#include <hip/hip_runtime.h>
#include <hip/hip_fp16.h>
#include <math.h>

// B=8, C=64, H=W=64, O=128, K=3, N=9, stride=1, pad=1
// ws layout (7.30 MB total):
//   xTh  @ 0        : fp16 [8][4096][64]          = 4,194,304 B
//   WtH  @ 4194304  : fp16 [9][128][64]           =   147,456 B
//   recP @ 4341760  : uint2 [9][32768]            = 2,359,296 B
//   modH @ 6701056  : fp16 [9][32768]             =   589,824 B

typedef _Float16 half8_t __attribute__((ext_vector_type(8)));
typedef float f32x4 __attribute__((ext_vector_type(4)));

// ---------------------------------------------------------------------------
// T1: x (B,C,H,W) f32 -> xTh (B, H*W, C) fp16
// ---------------------------------------------------------------------------
__global__ __launch_bounds__(256) void k_transpose_x(const float* __restrict__ x,
                                                     __half* __restrict__ xTh) {
    __shared__ float tile[64][65];
    int blk = blockIdx.x;
    int b = blk >> 6;
    int pt = blk & 63;
    int t = threadIdx.x;
    int lane = t & 63;
    int cq = t >> 6;
    const float* xb = x + ((size_t)b << 18);
#pragma unroll
    for (int r = 0; r < 16; ++r) {
        int c = cq * 16 + r;
        tile[c][lane] = xb[((size_t)c << 12) + pt * 64 + lane];
    }
    __syncthreads();
    int p = t >> 2, qc = t & 3;
    __align__(16) __half hv[16];
#pragma unroll
    for (int k = 0; k < 16; ++k) hv[k] = __float2half_rn(tile[qc * 16 + k][p]);
    __half* dst = xTh + ((size_t)b << 18) + (size_t)(pt * 64 + p) * 64 + qc * 16;
    ((uint4*)dst)[0] = ((uint4*)hv)[0];
    ((uint4*)dst)[1] = ((uint4*)hv)[1];
}

// ---------------------------------------------------------------------------
// T2: conv_w (O,C,3,3) f32 -> WtH (9, O, C) fp16
// ---------------------------------------------------------------------------
__global__ __launch_bounds__(256) void k_prep_w(const float* __restrict__ cw,
                                                __half* __restrict__ WtH) {
    int t = blockIdx.x * 256 + threadIdx.x;
    if (t >= 9 * 128 * 64) return;
    int c = t & 63;
    int o = (t >> 6) & 127;
    int n = t >> 13;
    WtH[t] = __float2half_rn(cw[(o * 64 + c) * 9 + n]);
}

// ---------------------------------------------------------------------------
// S1: 27-ch 3x3 conv (pad 1) + gather-record precompute.
//   grid 512 x 256 threads; block = 64 pixels x 4 c-quarters (2 waves/SIMD)
//   recP[n][pix] = uint2{ idx0|idx1<<12|gc0<<24|gc1<<26|gc2<<28|gc3<<30,
//                         idx2|idx3<<12 } ; modH[n][pix] = fp16(mod)
//   (g weights provably in {0,1,2} given the reference's int arithmetic)
// ---------------------------------------------------------------------------
__global__ __launch_bounds__(256) void k_stage1(
    const float* __restrict__ x, const float* __restrict__ shift_w,
    const float* __restrict__ shift_b, const float* __restrict__ mod_w,
    const float* __restrict__ mod_b, uint2* __restrict__ recP,
    __half* __restrict__ modH) {
    __shared__ float wl[576 * 28];   // [c*9+tap][ch(27 pad 28)]; tail reused as cbuf
    int t = threadIdx.x;

    for (int l = t; l < 18 * 576; l += 256) {
        int ch = l / 576, r = l % 576;
        wl[r * 28 + ch] = shift_w[l];
    }
    for (int l = t; l < 9 * 576; l += 256) {
        int ch = l / 576, r = l % 576;
        wl[r * 28 + 18 + ch] = mod_w[l];
    }
    __syncthreads();

    int pixl = t & 63;
    int q = t >> 6;                   // c-quarter 0..3
    int pix = blockIdx.x * 64 + pixl;
    int b = pix >> 12;
    int ii = (pix >> 6) & 63;
    int jj = pix & 63;
    const float* xb = x + ((size_t)b << 18);

    float acc[27];
#pragma unroll
    for (int ch = 0; ch < 27; ++ch) acc[ch] = 0.f;

    int c0 = q * 16;
    for (int c = c0; c < c0 + 16; ++c) {
        const float* xc = xb + ((size_t)c << 12);
#pragma unroll
        for (int tap = 0; tap < 9; ++tap) {
            int yi = ii + tap / 3 - 1;
            int yj = jj + tap % 3 - 1;
            float xv = 0.f;
            if ((unsigned)yi < 64u && (unsigned)yj < 64u) xv = xc[yi * 64 + yj];
            float wv[28];
            const float4* wr4 = (const float4*)&wl[(c * 9 + tap) * 28];
#pragma unroll
            for (int q4 = 0; q4 < 7; ++q4) *(float4*)&wv[q4 * 4] = wr4[q4];
#pragma unroll
            for (int ch = 0; ch < 27; ++ch) acc[ch] = fmaf(wv[ch], xv, acc[ch]);
        }
    }

    __syncthreads();
    float* cbuf = wl;                 // 3*64*27 = 5184 floats < 16128
    if (q) {
#pragma unroll
        for (int ch = 0; ch < 27; ++ch) cbuf[((q - 1) * 64 + pixl) * 27 + ch] = acc[ch];
    }
    __syncthreads();
    if (q == 0) {
#pragma unroll
        for (int p = 0; p < 3; ++p)
#pragma unroll
            for (int ch = 0; ch < 27; ++ch) acc[ch] += cbuf[(p * 64 + pixl) * 27 + ch];

#pragma unroll
        for (int n = 0; n < 9; ++n) {
            float px = ((acc[n] + shift_b[n]) + (float)(n / 3 - 1)) + (float)(ii + 1);
            float py = ((acc[9 + n] + shift_b[9 + n]) + (float)(n % 3 - 1)) + (float)(jj + 1);
            float mz = acc[18 + n] + mod_b[n];
            float mod = 1.f / (1.f + expf(-mz));

            float fx = floorf(px), fy = floorf(py);
            int ltx = (int)fminf(fmaxf(fx, 0.f), 63.f);
            int lty = (int)fminf(fmaxf(fy, 0.f), 63.f);
            int rbx = (int)fminf(fmaxf(fx + 1.f, 0.f), 63.f);
            int rby = (int)fminf(fmaxf(fy + 1.f, 0.f), 63.f);
            int pxi = (int)fminf(fmaxf(px, 0.f), 63.f);
            int pyi = (int)fminf(fmaxf(py, 0.f), 63.f);

            int g_lt = (1 + ltx - pxi) * (1 + lty - pyi);
            int g_rb = (1 - rbx + pxi) * (1 - rby + pyi);
            int g_lb = (1 + ltx - pxi) * (1 + rby - pyi);
            int g_rt = (1 - rbx + pxi) * (1 - lty + pyi);

            int qxa[4] = {ltx, rbx, ltx, rbx};
            int qya[4] = {lty, rby, rby, lty};
            int gga[4] = {g_lt, g_rb, g_lb, g_rt};
            unsigned w0 = 0, w1 = 0;
#pragma unroll
            for (int j = 0; j < 4; ++j) {
                bool valid = (qxa[j] >= 1) && (qya[j] >= 1);
                unsigned idx = valid ? (unsigned)((qxa[j] - 1) * 64 + (qya[j] - 1)) : 0u;
                unsigned gc = valid ? (unsigned)gga[j] : 0u;   // 0..2
                if (j < 2) w0 |= idx << (12 * j); else w1 |= idx << (12 * (j - 2));
                w0 |= gc << (24 + 2 * j);
            }
            recP[n * 32768 + pix] = make_uint2(w0, w1);
            modH[n * 32768 + pix] = __float2half_rn(mod);
        }
    }
}

// ---------------------------------------------------------------------------
// Main MFMA GEMM: out[pix][o] = sum_n sum_c A_n[pix][c] * W_n[c][o]
//   grid 256 x 512 threads (8 waves: wm=w>>1 in 0..3 (M), wn=w&1 (N))
//   tile 128 pix x 128 o; wave-tile 32x64; mfma_f32_16x16x32_f16
//   A: fp16 LDS [128][64], XOR-granule swizzle ^((row&7)<<4) -> conflict-free
//   B: fragments loaded straight from global (W is L2-resident, 144 KB)
// ---------------------------------------------------------------------------
__global__ __launch_bounds__(512, 2) void k_main(
    const __half* __restrict__ xTh, const __half* __restrict__ WtH,
    const uint2* __restrict__ recP, const __half* __restrict__ modH,
    float* __restrict__ out) {
    __shared__ __align__(16) unsigned char AlB[16384];   // A tile fp16 [128][64] swizzled
    __shared__ __align__(16) float Ep[4096];             // epilogue 32 o x 128 m

    int t = threadIdx.x;
    int l = t & 63;
    int w = t >> 6;
    int wm = w >> 1, wn = w & 1;
    int pix0 = blockIdx.x * 128;
    int b = pix0 >> 12;
    int pbase = pix0 & 4095;
    const __half* xb = xTh + ((size_t)b << 18);
    int l15 = l & 15, lhi = l >> 4;

    f32x4 acc[2][4];
#pragma unroll
    for (int f = 0; f < 2; ++f)
#pragma unroll
        for (int g = 0; g < 4; ++g) acc[f][g] = (f32x4){0.f, 0.f, 0.f, 0.f};

    for (int n = 0; n < 9; ++n) {
        // B fragments direct from global: o = wn*64 + g*16 + l15, c = ks*32 + lhi*8
        const __half* Wn = WtH + n * 8192;
        uint4 Bv[2][4];
#pragma unroll
        for (int ks = 0; ks < 2; ++ks)
#pragma unroll
            for (int g = 0; g < 4; ++g)
                Bv[ks][g] = *(const uint4*)(Wn + ((wn * 64 + g * 16 + l15) << 6) +
                                            ks * 32 + (lhi << 3));

        // A build: 1024 tasks (128 m x 8 cg), 2 per thread
        const uint2* recN = recP + n * 32768 + pix0;
        const __half* modN = modH + n * 32768 + pix0;
#pragma unroll
        for (int r = 0; r < 2; ++r) {
            int task = r * 512 + t;
            int m = task >> 3;
            int cg = task & 7;
            uint2 rc = recN[m];
            float mod = __half2float(modN[m]);
            int id[4] = {(int)(rc.x & 0xFFF), (int)((rc.x >> 12) & 0xFFF),
                         (int)(rc.y & 0xFFF), (int)((rc.y >> 12) & 0xFFF)};
            __align__(16) __half2 a[4];
            a[0] = __half2(0, 0); a[1] = __half2(0, 0);
            a[2] = __half2(0, 0); a[3] = __half2(0, 0);
#pragma unroll
            for (int j = 0; j < 4; ++j) {
                float wf = (float)((rc.x >> (24 + 2 * j)) & 3) * mod;
                __half2 wh = __half2(__float2half_rn(wf), __float2half_rn(wf));
                uint4 v = *(const uint4*)(xb + (id[j] << 6) + (cg << 3));
                const __half2* vv = (const __half2*)&v;
                a[0] = __hfma2(wh, vv[0], a[0]);
                a[1] = __hfma2(wh, vv[1], a[1]);
                a[2] = __hfma2(wh, vv[2], a[2]);
                a[3] = __hfma2(wh, vv[3], a[3]);
            }
            *(uint4*)&AlB[(m << 7) | ((cg ^ (m & 7)) << 4)] = *(uint4*)a;
        }
        __syncthreads();

        // MFMA: A rows wm*32 + f*16 + l15, k = ks*32 + lhi*8
#pragma unroll
        for (int ks = 0; ks < 2; ++ks) {
            half8_t Af[2];
#pragma unroll
            for (int f = 0; f < 2; ++f) {
                int row = wm * 32 + f * 16 + l15;
                int gr = (ks * 4 + lhi) ^ (row & 7);
                Af[f] = *(const half8_t*)&AlB[(row << 7) | (gr << 4)];
            }
#pragma unroll
            for (int f = 0; f < 2; ++f)
#pragma unroll
                for (int g = 0; g < 4; ++g) {
                    half8_t Bf = *(half8_t*)&Bv[ks][g];
                    acc[f][g] = __builtin_amdgcn_mfma_f32_16x16x32_f16(
                        Af[f], Bf, acc[f][g], 0, 0, 0);
                }
        }
        __syncthreads();
    }

    // Epilogue via LDS: 4 rounds of 32 o-rows -> coalesced float4 stores
    float* ob = out + ((size_t)b << 19);
#pragma unroll
    for (int r = 0; r < 4; ++r) {
        if (wn == (r >> 1)) {
#pragma unroll
            for (int f = 0; f < 2; ++f)
#pragma unroll
                for (int gg = 0; gg < 2; ++gg) {
                    int g = (r & 1) * 2 + gg;
                    int o_loc = (g & 1) * 16 + l15;
                    int m4 = wm * 8 + f * 4 + lhi;    // granule = m/4
                    int gr = m4 ^ (o_loc & 7);
                    *(f32x4*)&Ep[(o_loc << 7) + (gr << 2)] = acc[f][g];
                }
        }
        __syncthreads();
        {
            int o_loc = t >> 4;
            int mseg = t & 15;
            int g1 = mseg ^ (o_loc & 7);
            int g2 = (16 + mseg) ^ (o_loc & 7);
            float4 fa = *(float4*)&Ep[(o_loc << 7) + (g1 << 2)];
            float4 fb = *(float4*)&Ep[(o_loc << 7) + (g2 << 2)];
            float* dst = ob + ((size_t)(r * 32 + o_loc) << 12) + pbase;
            *(float4*)(dst + mseg * 4) = fa;
            *(float4*)(dst + 64 + mseg * 4) = fb;
        }
        __syncthreads();
    }
}

// ---------------------------------------------------------------------------
extern "C" void kernel_launch(void* const* d_in, const int* in_sizes, int n_in,
                              void* d_out, int out_size, void* d_ws, size_t ws_size,
                              hipStream_t stream) {
    const float* x = (const float*)d_in[0];
    const float* shift_w = (const float*)d_in[1];
    const float* shift_b = (const float*)d_in[2];
    const float* mod_w = (const float*)d_in[3];
    const float* mod_b = (const float*)d_in[4];
    const float* conv_w = (const float*)d_in[5];
    float* out = (float*)d_out;

    char* ws = (char*)d_ws;
    __half* xTh = (__half*)ws;                       // 4 MB
    __half* WtH = (__half*)(ws + 4194304);           // 144 KB
    uint2* recP = (uint2*)(ws + 4341760);            // 2.25 MB
    __half* modH = (__half*)(ws + 6701056);          // 576 KB  (total 7.30 MB)

    k_transpose_x<<<dim3(512), dim3(256), 0, stream>>>(x, xTh);
    k_prep_w<<<dim3(288), dim3(256), 0, stream>>>(conv_w, WtH);
    k_stage1<<<dim3(512), dim3(256), 0, stream>>>(x, shift_w, shift_b, mod_w,
                                                  mod_b, recP, modH);
    k_main<<<dim3(256), dim3(512), 0, stream>>>(xTh, WtH, recP, modH, out);
}

// Round 4
// 83.331 us; speedup vs baseline: 1.7676x; 1.1163x over previous
//
#include <hip/hip_runtime.h>
#include <hip/hip_fp16.h>
#include <math.h>

// B=8, C=64, H=W=64, O=128, K=3, N=9, stride=1, pad=1
// ws layout (7.36 MB total):
//   xTh  @ 0        : fp16 [8][4096][64]          = 4,194,304 B
//   WtH  @ 4194304  : fp16 [9][128][64]           =   147,456 B
//   recP @ 4341760  : uint2 [9][32768]            = 2,359,296 B
//   modH @ 6701056  : fp16 [9][32768]             =   589,824 B
//   wOrd @ 7290880  : f32  [576][28]              =    64,512 B

typedef _Float16 half8_t __attribute__((ext_vector_type(8)));
typedef float f32x4 __attribute__((ext_vector_type(4)));

// ---------------------------------------------------------------------------
// T1: x (B,C,H,W) f32 -> xTh (B, H*W, C) fp16
// ---------------------------------------------------------------------------
__global__ __launch_bounds__(256) void k_transpose_x(const float* __restrict__ x,
                                                     __half* __restrict__ xTh) {
    __shared__ float tile[64][65];
    int blk = blockIdx.x;
    int b = blk >> 6;
    int pt = blk & 63;
    int t = threadIdx.x;
    int lane = t & 63;
    int cq = t >> 6;
    const float* xb = x + ((size_t)b << 18);
#pragma unroll
    for (int r = 0; r < 16; ++r) {
        int c = cq * 16 + r;
        tile[c][lane] = xb[((size_t)c << 12) + pt * 64 + lane];
    }
    __syncthreads();
    int p = t >> 2, qc = t & 3;
    __align__(16) __half hv[16];
#pragma unroll
    for (int k = 0; k < 16; ++k) hv[k] = __float2half_rn(tile[qc * 16 + k][p]);
    __half* dst = xTh + ((size_t)b << 18) + (size_t)(pt * 64 + p) * 64 + qc * 16;
    ((uint4*)dst)[0] = ((uint4*)hv)[0];
    ((uint4*)dst)[1] = ((uint4*)hv)[1];
}

// ---------------------------------------------------------------------------
// T2: conv_w (O,C,3,3) f32 -> WtH (9, O, C) fp16
// ---------------------------------------------------------------------------
__global__ __launch_bounds__(256) void k_prep_w(const float* __restrict__ cw,
                                                __half* __restrict__ WtH) {
    int t = blockIdx.x * 256 + threadIdx.x;
    if (t >= 9 * 128 * 64) return;
    int c = t & 63;
    int o = (t >> 6) & 127;
    int n = t >> 13;
    WtH[t] = __float2half_rn(cw[(o * 64 + c) * 9 + n]);
}

// ---------------------------------------------------------------------------
// T3: stage-1 weights -> wOrd[(c*9+tap)*28 + ch]  (ch 0..17 shift, 18..26 mod)
// ---------------------------------------------------------------------------
__global__ __launch_bounds__(256) void k_prep_s1(const float* __restrict__ shift_w,
                                                 const float* __restrict__ mod_w,
                                                 float* __restrict__ wOrd) {
    int t = blockIdx.x * 256 + threadIdx.x;
    if (t >= 576 * 28) return;
    int ch = t % 28;
    int r = t / 28;            // r = c*9 + tap
    int c = r / 9, tap = r % 9;
    float v = 0.f;
    if (ch < 18) v = shift_w[(ch * 64 + c) * 9 + tap];
    else if (ch < 27) v = mod_w[((ch - 18) * 64 + c) * 9 + tap];
    wOrd[t] = v;
}

// ---------------------------------------------------------------------------
// S1: 27-ch 3x3 conv (pad 1) + gather-record precompute.
//   grid 512 x 256; block = 64 pixels (one image row) x 4 c-quarters.
//   Weights come from wOrd via WAVE-UNIFORM addresses -> scalar loads (SGPR),
//   zero LDS weight traffic.  LDS only for the 4-way partial reduction.
//   Tail (records for 9 taps) split across waves q=0..2 (3 n's each).
// ---------------------------------------------------------------------------
__global__ __launch_bounds__(256) void k_stage1(
    const float* __restrict__ x, const float* __restrict__ wOrd,
    const float* __restrict__ shift_b, const float* __restrict__ mod_b,
    uint2* __restrict__ recP, __half* __restrict__ modH) {
    __shared__ float cbuf[4 * 64 * 27];   // 27648 B
    int t = threadIdx.x;
    int pixl = t & 63;
    int q = __builtin_amdgcn_readfirstlane(t >> 6);   // wave-uniform c-quarter
    int pix = blockIdx.x * 64 + pixl;
    int b = pix >> 12;
    int ii = (pix >> 6) & 63;
    int jj = pix & 63;
    const float* xb = x + ((size_t)b << 18);

    float acc[27];
#pragma unroll
    for (int ch = 0; ch < 27; ++ch) acc[ch] = 0.f;

    for (int c = q * 16; c < q * 16 + 16; ++c) {
        const float* xc = xb + ((size_t)c << 12);
        float xv[9];
#pragma unroll
        for (int tap = 0; tap < 9; ++tap) {
            int yi = ii + tap / 3 - 1;
            int yj = jj + tap % 3 - 1;
            xv[tap] = ((unsigned)yi < 64u && (unsigned)yj < 64u)
                          ? xc[yi * 64 + yj] : 0.f;
        }
        const float* wp = wOrd + c * 9 * 28;   // wave-uniform -> s_load
#pragma unroll
        for (int tap = 0; tap < 9; ++tap)
#pragma unroll
            for (int ch = 0; ch < 27; ++ch)
                acc[ch] = fmaf(wp[tap * 28 + ch], xv[tap], acc[ch]);
    }

    // 4-way reduction via LDS
#pragma unroll
    for (int ch = 0; ch < 27; ++ch) cbuf[q * 1728 + pixl * 27 + ch] = acc[ch];
    __syncthreads();

    if (q < 3) {
        float s[27];
#pragma unroll
        for (int ch = 0; ch < 27; ++ch)
            s[ch] = (cbuf[pixl * 27 + ch] + cbuf[1728 + pixl * 27 + ch]) +
                    (cbuf[3456 + pixl * 27 + ch] + cbuf[5184 + pixl * 27 + ch]);

#pragma unroll
        for (int k = 0; k < 3; ++k) {
            int n = q * 3 + k;
            float px = ((s[n] + shift_b[n]) + (float)(n / 3 - 1)) + (float)(ii + 1);
            float py = ((s[9 + n] + shift_b[9 + n]) + (float)(n % 3 - 1)) + (float)(jj + 1);
            float mz = s[18 + n] + mod_b[n];
            float mod = 1.f / (1.f + expf(-mz));

            float fx = floorf(px), fy = floorf(py);
            int ltx = (int)fminf(fmaxf(fx, 0.f), 63.f);
            int lty = (int)fminf(fmaxf(fy, 0.f), 63.f);
            int rbx = (int)fminf(fmaxf(fx + 1.f, 0.f), 63.f);
            int rby = (int)fminf(fmaxf(fy + 1.f, 0.f), 63.f);
            int pxi = (int)fminf(fmaxf(px, 0.f), 63.f);
            int pyi = (int)fminf(fmaxf(py, 0.f), 63.f);

            int g_lt = (1 + ltx - pxi) * (1 + lty - pyi);
            int g_rb = (1 - rbx + pxi) * (1 - rby + pyi);
            int g_lb = (1 + ltx - pxi) * (1 + rby - pyi);
            int g_rt = (1 - rbx + pxi) * (1 - lty + pyi);

            int qxa[4] = {ltx, rbx, ltx, rbx};
            int qya[4] = {lty, rby, rby, lty};
            int gga[4] = {g_lt, g_rb, g_lb, g_rt};
            unsigned w0 = 0, w1 = 0;
#pragma unroll
            for (int j = 0; j < 4; ++j) {
                bool valid = (qxa[j] >= 1) && (qya[j] >= 1);
                unsigned idx = valid ? (unsigned)((qxa[j] - 1) * 64 + (qya[j] - 1)) : 0u;
                unsigned gc = valid ? (unsigned)gga[j] : 0u;   // 0..2
                if (j < 2) w0 |= idx << (12 * j); else w1 |= idx << (12 * (j - 2));
                w0 |= gc << (24 + 2 * j);
            }
            recP[n * 32768 + pix] = make_uint2(w0, w1);
            modH[n * 32768 + pix] = __float2half_rn(mod);
        }
    }
}

// ---------------------------------------------------------------------------
// Main MFMA GEMM: out[pix][o] = sum_n sum_c A_n[pix][c] * W_n[c][o]
//   grid 512 x 256 threads (4 waves: wm=w>>1 (M), wn=w&1 (N)) -> 2 blocks/CU
//   tile 64 pix x 128 o; wave-tile 32x64; mfma_f32_16x16x32_f16
//   A: fp16 LDS [64][64], XOR-granule swizzle ^((row&7)<<4) -> conflict-free
//   B: fragments loaded straight from global (W is L2-resident, 144 KB)
// ---------------------------------------------------------------------------
__global__ __launch_bounds__(256, 2) void k_main(
    const __half* __restrict__ xTh, const __half* __restrict__ WtH,
    const uint2* __restrict__ recP, const __half* __restrict__ modH,
    float* __restrict__ out) {
    __shared__ __align__(16) unsigned char AlB[8192];   // A tile fp16 [64][64] swizzled
    __shared__ __align__(16) float Ep[2048];            // epilogue 32 o x 64 m

    int t = threadIdx.x;
    int l = t & 63;
    int w = t >> 6;
    int wm = w >> 1, wn = w & 1;
    int pix0 = blockIdx.x * 64;
    int b = pix0 >> 12;
    int pbase = pix0 & 4095;
    const __half* xb = xTh + ((size_t)b << 18);
    int l15 = l & 15, lhi = l >> 4;

    f32x4 acc[2][4];
#pragma unroll
    for (int f = 0; f < 2; ++f)
#pragma unroll
        for (int g = 0; g < 4; ++g) acc[f][g] = (f32x4){0.f, 0.f, 0.f, 0.f};

    for (int n = 0; n < 9; ++n) {
        // B fragments direct from global: o = wn*64 + g*16 + l15, c = ks*32 + lhi*8
        const __half* Wn = WtH + n * 8192;
        uint4 Bv[2][4];
#pragma unroll
        for (int ks = 0; ks < 2; ++ks)
#pragma unroll
            for (int g = 0; g < 4; ++g)
                Bv[ks][g] = *(const uint4*)(Wn + ((wn * 64 + g * 16 + l15) << 6) +
                                            ks * 32 + (lhi << 3));

        // A build: 512 tasks (64 m x 8 cg), 2 per thread
        const uint2* recN = recP + n * 32768 + pix0;
        const __half* modN = modH + n * 32768 + pix0;
#pragma unroll
        for (int r = 0; r < 2; ++r) {
            int task = r * 256 + t;
            int m = task >> 3;
            int cg = task & 7;
            uint2 rc = recN[m];
            float mod = __half2float(modN[m]);
            int id[4] = {(int)(rc.x & 0xFFF), (int)((rc.x >> 12) & 0xFFF),
                         (int)(rc.y & 0xFFF), (int)((rc.y >> 12) & 0xFFF)};
            __align__(16) __half2 a[4];
            a[0] = __half2(0, 0); a[1] = __half2(0, 0);
            a[2] = __half2(0, 0); a[3] = __half2(0, 0);
#pragma unroll
            for (int j = 0; j < 4; ++j) {
                float wf = (float)((rc.x >> (24 + 2 * j)) & 3) * mod;
                __half2 wh = __half2(__float2half_rn(wf), __float2half_rn(wf));
                uint4 v = *(const uint4*)(xb + (id[j] << 6) + (cg << 3));
                const __half2* vv = (const __half2*)&v;
                a[0] = __hfma2(wh, vv[0], a[0]);
                a[1] = __hfma2(wh, vv[1], a[1]);
                a[2] = __hfma2(wh, vv[2], a[2]);
                a[3] = __hfma2(wh, vv[3], a[3]);
            }
            *(uint4*)&AlB[(m << 7) | ((cg ^ (m & 7)) << 4)] = *(uint4*)a;
        }
        __syncthreads();

        // MFMA: A rows wm*32 + f*16 + l15, k = ks*32 + lhi*8
#pragma unroll
        for (int ks = 0; ks < 2; ++ks) {
            half8_t Af[2];
#pragma unroll
            for (int f = 0; f < 2; ++f) {
                int row = wm * 32 + f * 16 + l15;
                int gr = (ks * 4 + lhi) ^ (row & 7);
                Af[f] = *(const half8_t*)&AlB[(row << 7) | (gr << 4)];
            }
#pragma unroll
            for (int f = 0; f < 2; ++f)
#pragma unroll
                for (int g = 0; g < 4; ++g) {
                    half8_t Bf = *(half8_t*)&Bv[ks][g];
                    acc[f][g] = __builtin_amdgcn_mfma_f32_16x16x32_f16(
                        Af[f], Bf, acc[f][g], 0, 0, 0);
                }
        }
        __syncthreads();
    }

    // Epilogue via LDS: 4 rounds of 32 o-rows -> coalesced float4 stores
    float* ob = out + ((size_t)b << 19);
#pragma unroll
    for (int r = 0; r < 4; ++r) {
        if (wn == (r >> 1)) {
#pragma unroll
            for (int f = 0; f < 2; ++f)
#pragma unroll
                for (int gg = 0; gg < 2; ++gg) {
                    int g = (r & 1) * 2 + gg;
                    int o_loc = gg * 16 + l15;
                    int m4 = wm * 8 + f * 4 + lhi;    // granule = m/4, 0..15
                    int gr = m4 ^ (o_loc & 7);
                    *(f32x4*)&Ep[(o_loc << 6) + (gr << 2)] = acc[f][g];
                }
        }
        __syncthreads();
        {
            int o_loc = t >> 3;          // 0..31
            int mseg = t & 7;            // 0..7
            int g1 = mseg ^ (o_loc & 7);
            int g2 = (8 + mseg) ^ (o_loc & 7);
            float4 fa = *(float4*)&Ep[(o_loc << 6) + (g1 << 2)];
            float4 fb = *(float4*)&Ep[(o_loc << 6) + (g2 << 2)];
            float* dst = ob + ((size_t)(r * 32 + o_loc) << 12) + pbase;
            *(float4*)(dst + mseg * 4) = fa;
            *(float4*)(dst + 32 + mseg * 4) = fb;
        }
        __syncthreads();
    }
}

// ---------------------------------------------------------------------------
extern "C" void kernel_launch(void* const* d_in, const int* in_sizes, int n_in,
                              void* d_out, int out_size, void* d_ws, size_t ws_size,
                              hipStream_t stream) {
    const float* x = (const float*)d_in[0];
    const float* shift_w = (const float*)d_in[1];
    const float* shift_b = (const float*)d_in[2];
    const float* mod_w = (const float*)d_in[3];
    const float* mod_b = (const float*)d_in[4];
    const float* conv_w = (const float*)d_in[5];
    float* out = (float*)d_out;

    char* ws = (char*)d_ws;
    __half* xTh = (__half*)ws;                       // 4 MB
    __half* WtH = (__half*)(ws + 4194304);           // 144 KB
    uint2* recP = (uint2*)(ws + 4341760);            // 2.25 MB
    __half* modH = (__half*)(ws + 6701056);          // 576 KB
    float* wOrd = (float*)(ws + 7290880);            // 63 KB   (total 7.36 MB)

    k_transpose_x<<<dim3(512), dim3(256), 0, stream>>>(x, xTh);
    k_prep_w<<<dim3(288), dim3(256), 0, stream>>>(conv_w, WtH);
    k_prep_s1<<<dim3(63), dim3(256), 0, stream>>>(shift_w, mod_w, wOrd);
    k_stage1<<<dim3(512), dim3(256), 0, stream>>>(x, wOrd, shift_b, mod_b,
                                                  recP, modH);
    k_main<<<dim3(512), dim3(256), 0, stream>>>(xTh, WtH, recP, modH, out);
}